// Round 1
// 762.096 us; speedup vs baseline: 1.0855x; 1.0855x over previous
//
#include <hip/hip_runtime.h>
#include <stdint.h>

// ---------------------------------------------------------------------------
// Subgraph GNN: out = sum_k MLP_k(hops_k), hops = [X, hop1@X, hop2@X, hop3@X]
// N=8192, IN_DIM=64, H1=128, H2=64, 4 branches.
//
// R3 changes vs R2 (hop_gemm was DRAM-inefficiency-bound: A loads were
// 16 rows x 16B chunks at 32KB stride per instruction -> ~98k concurrent
// 128B DRAM streams, 1.54 TB/s):
//   - hop_gemm: LDS-staged A tiles via global_load_lds_dwordx4. Each staging
//     instruction reads 1 KB CONTIGUOUS from one A row (64 lanes x 16B) ->
//     large DRAM bursts, 16 full lines/instr. Tile = 16 rows x 256 floats
//     (16 KB), double-buffered (32 KB -> 5 blocks/CU). Waves K-split within
//     the tile (2 MFMA k-steps each); same verified frag/reduce/store code.
//   - LDS bank conflicts on fragment reads (row stride 1KB == 0 mod 128B)
//     fixed with XOR swizzle byte ^= (row&7)<<4, applied as a pre-swizzle on
//     the per-lane GLOBAL source address (global_load_lds writes linearly;
//     source-permute + read-swizzle must be the same involution).
//   - prep / mlp unchanged (isolate the hop_gemm change).
// ---------------------------------------------------------------------------

#define N_NODES 8192
#define NDIM 64
#define K_TILE 256                 // floats of K per staged tile
#define NT (N_NODES / K_TILE)      // 32 tiles

typedef __attribute__((ext_vector_type(8))) short short8;   // 8 bf16 (4 VGPRs)
typedef __attribute__((ext_vector_type(4))) float f32x4;    // MFMA C/D

__device__ __forceinline__ unsigned int f2bf(float f) {
  // round-to-nearest-even fp32 -> bf16 bit pattern (data is finite)
  unsigned int u = __builtin_bit_cast(unsigned int, f);
  u += 0x7fffu + ((u >> 16) & 1u);
  return u >> 16;
}

__device__ __forceinline__ void async_copy16(void* lds, const void* g) {
  // 64 lanes x 16B: global[per-lane addr] -> LDS[uniform base + lane*16]
  __builtin_amdgcn_global_load_lds(
      (const __attribute__((address_space(1))) void*)g,
      (__attribute__((address_space(3))) void*)lds, 16, 0, 0);
}

// ---------------------------------------------------------------------------
// prep: Bp[((k>>3)*64 + n)*8 + (k&7)] = X[k][n]  (bf16), X = cat(x, wf)
// ---------------------------------------------------------------------------
__global__ void prep_kernel(const float* __restrict__ x,
                            const float* __restrict__ wf,
                            unsigned short* __restrict__ Bp) {
  int s = blockIdx.x * 256 + threadIdx.x;     // 0 .. 524287
  int khi = s >> 9;                           // k / 8
  int rem = s & 511;
  int n   = rem >> 3;
  int klo = rem & 7;
  int k   = (khi << 3) | klo;
  float v = (n < 48) ? x[k * 48 + n] : wf[k * 16 + (n - 48)];
  Bp[s] = (unsigned short)f2bf(v);
}

// ---------------------------------------------------------------------------
// hop_gemm: Y[h] = hop_h @ X   (M=8192, N=64, K=8192)
// grid = 1536 blocks (3 hops x 512 m-tiles of 16 rows), 256 threads (4 waves).
// Per tile t (K_TILE=256 floats): stage A[16 rows][t*256..+256) to LDS with
// 16 x global_load_lds_dwordx4 (4 per wave, 1 KB contiguous of one row each);
// wave w computes k-substeps [w*64, w*64+64) = 2 MFMA k-steps x 4 n-frags.
// Partial 16x64 tiles summed through LDS (reuse buffer) and stored once.
// A frag: lane holds A[m=lane&15][k0 + (lane>>4)*8 + j], j=0..7.
// C/D: col = lane&15, row = (lane>>4)*4 + reg  (m89/m91-verified layout).
// ---------------------------------------------------------------------------
__global__ __launch_bounds__(256, 5) void hop_gemm(
    const float* __restrict__ hop1,
    const float* __restrict__ hop2,
    const float* __restrict__ hop3,
    const unsigned short* __restrict__ Bp,
    float* __restrict__ Y) {
  // 2 x (16 rows x 256 floats) double buffer = 32 KB -> 5 blocks/CU
  __shared__ __attribute__((aligned(16))) float bufA[2][16 * K_TILE];

  int bid  = blockIdx.x;
  int h    = bid % 3;
  int mblk = bid / 3;
  const float* A = (h == 0) ? hop1 : (h == 1) ? hop2 : hop3;

  int tid  = threadIdx.x;
  int w    = tid >> 6;          // wave id
  int lane = tid & 63;
  int n0   = lane & 15;         // frag row (A rows) / output col within n-tile
  int q    = lane >> 4;
  int lane16 = lane << 4;

  const short8* Bp8 = (const short8*)Bp;

  // Per-wave staging sources: rows w*4 .. w*4+3, 1 KB contiguous per tile,
  // per-lane XOR pre-swizzle (involution, stays within the 1 KB chunk).
  const char* gA[4];
  int ldsOff[4];
#pragma unroll
  for (int i = 0; i < 4; ++i) {
    int row = w * 4 + i;
    gA[i] = (const char*)A + ((size_t)(mblk * 16 + row) << 15)   // row*8192*4B
            + (unsigned)(lane16 ^ ((row & 7) << 4));
    ldsOff[i] = row << 10;                                       // row*1024B
  }

  f32x4 acc0 = {0.f, 0.f, 0.f, 0.f};
  f32x4 acc1 = {0.f, 0.f, 0.f, 0.f};
  f32x4 acc2 = {0.f, 0.f, 0.f, 0.f};
  f32x4 acc3 = {0.f, 0.f, 0.f, 0.f};

  int swz = (n0 & 7) << 4;     // read-side swizzle for this lane's frag row

#define STAGE(tt)                                                  \
  do {                                                             \
    char* db = (char*)bufA[(tt) & 1];                              \
    _Pragma("unroll")                                              \
    for (int i = 0; i < 4; ++i) {                                  \
      async_copy16(db + ldsOff[i], gA[i] + ((size_t)(tt) << 10));  \
    }                                                              \
  } while (0)

  // One MFMA k-step: 32 k-values starting at within-tile float offset
  // w*64 + s*32. LDS read: row n0, logical bytes 4*k0 + 32q (+16), swizzled.
#define KSTEP(lbuf, khb, s)                                                  \
  do {                                                                       \
    int off0 = (n0 << 10) + ((((w << 8) + ((s) << 7)) + (q << 5)) ^ swz);    \
    float4 a0 = *(const float4*)((const char*)(lbuf) + off0);                \
    float4 a1 = *(const float4*)((const char*)(lbuf) + (off0 ^ 16));         \
    const short8* bp = Bp8 + (size_t)(((khb) + (s) * 4 + q) * 64 + n0);      \
    short8 b0 = bp[0], b1 = bp[16], b2 = bp[32], b3 = bp[48];                \
    union { short8 v; unsigned int u[4]; } af;                               \
    af.u[0] = (f2bf(a0.y) << 16) | f2bf(a0.x);                               \
    af.u[1] = (f2bf(a0.w) << 16) | f2bf(a0.z);                               \
    af.u[2] = (f2bf(a1.y) << 16) | f2bf(a1.x);                               \
    af.u[3] = (f2bf(a1.w) << 16) | f2bf(a1.z);                               \
    acc0 = __builtin_amdgcn_mfma_f32_16x16x32_bf16(af.v, b0, acc0, 0, 0, 0); \
    acc1 = __builtin_amdgcn_mfma_f32_16x16x32_bf16(af.v, b1, acc1, 0, 0, 0); \
    acc2 = __builtin_amdgcn_mfma_f32_16x16x32_bf16(af.v, b2, acc2, 0, 0, 0); \
    acc3 = __builtin_amdgcn_mfma_f32_16x16x32_bf16(af.v, b3, acc3, 0, 0, 0); \
  } while (0)

  STAGE(0);
  __syncthreads();             // drains vmcnt -> tile 0 resident

#pragma unroll 1
  for (int t = 0; t < NT - 1; ++t) {
    STAGE(t + 1);                          // issue next tile's 16 x 1KB loads
    const float* lbuf = bufA[t & 1];
    int khb = t * 32 + w * 8;              // short8-row base for B this tile
    KSTEP(lbuf, khb, 0);
    KSTEP(lbuf, khb, 1);
    __syncthreads();           // vmcnt(0)+lgkmcnt(0)+barrier: t+1 ready,
                               // everyone done reading buf[t&1]
  }
  {
    const float* lbuf = bufA[(NT - 1) & 1];
    int khb = (NT - 1) * 32 + w * 8;
    KSTEP(lbuf, khb, 0);
    KSTEP(lbuf, khb, 1);
  }

#undef STAGE
#undef KSTEP

  // ---- cross-wave K reduction through LDS (reuse bufA[0] region: 16 KB) ----
  // Final tile was read from bufA[1]; bufA[0]'s last readers synced at the
  // end of iteration t=30, so per-wave disjoint writes below are race-free.
  float* red = (float*)bufA;
  {
    float* rw = red + w * 1024 + lane * 4;
    *(f32x4*)(rw)       = acc0;   // nt=0
    *(f32x4*)(rw + 256) = acc1;   // nt=1
    *(f32x4*)(rw + 512) = acc2;   // nt=2
    *(f32x4*)(rw + 768) = acc3;   // nt=3
  }
  __syncthreads();

  {
    int t = tid;                      // 0..255 = nt(2b) | lane(6b)
    f32x4 v = *(const f32x4*)&red[t * 4];
    v += *(const f32x4*)&red[1024 + t * 4];
    v += *(const f32x4*)&red[2048 + t * 4];
    v += *(const f32x4*)&red[3072 + t * 4];

    int nt    = t >> 6;
    int lane2 = t & 63;
    int q2    = lane2 >> 4;
    int n02   = lane2 & 15;
    int col   = nt * 16 + n02;
    float* Yo = Y + (size_t)h * (N_NODES * NDIM)
                  + (size_t)(mblk * 16 + q2 * 4) * NDIM + col;
    Yo[0 * NDIM] = v.x;
    Yo[1 * NDIM] = v.y;
    Yo[2 * NDIM] = v.z;
    Yo[3 * NDIM] = v.w;
  }
}

// ---------------------------------------------------------------------------
// mlp: out[row] = sum_k ( relu(Y_k[row] @ W1_k + b1_k) @ W2_k + b2_k )
// 512 blocks x 256 threads, 16 rows/block. fp32 VALU. Weights read straight
// from global (every block reads the same 256 KB -> L1/L2 resident).
// ---------------------------------------------------------------------------
#define YS_LD 68
#define HS_LD 132
__global__ __launch_bounds__(256) void mlp_kernel(
    const float* __restrict__ x, const float* __restrict__ wf,
    const float* __restrict__ Y,          // [3][8192][64]
    const float* __restrict__ W1, const float* __restrict__ b1,
    const float* __restrict__ W2, const float* __restrict__ b2,
    float* __restrict__ out) {
  __shared__ __attribute__((aligned(16))) float Ys[16 * YS_LD];   // 4.25 KB
  __shared__ __attribute__((aligned(16))) float Hs[16 * HS_LD];   // 8.25 KB
  __shared__ float b1s[128];
  __shared__ float b2s[64];

  int t = threadIdx.x;
  int rowBase = blockIdx.x * 16;

  int r  = t >> 4;           // 0..15: row (both layers)
  int c8 = (t & 15) * 8;     // layer-1 cols
  int c4 = (t & 15) * 4;     // layer-2 cols

  float oacc[4] = {0.f, 0.f, 0.f, 0.f};

  for (int k = 0; k < 4; ++k) {
    // ---- stage activations + biases ----
    for (int i = t; i < 16 * 64; i += 256) {
      int row = i >> 6;
      int n   = i & 63;
      float v;
      if (k == 0) {
        int grow = rowBase + row;
        v = (n < 48) ? x[grow * 48 + n] : wf[grow * 16 + (n - 48)];
      } else {
        v = Y[(size_t)(k - 1) * (N_NODES * 64) + (size_t)(rowBase + row) * 64 + n];
      }
      Ys[row * YS_LD + n] = v;
    }
    if (t < 128) b1s[t] = b1[k * 128 + t];
    else if (t < 192) b2s[t - 128] = b2[k * 64 + (t - 128)];
    __syncthreads();

    // ---- layer 1: H = relu(Ys @ W1 + b1), thread = 1 row x 8 cols ----
    const float* W1k = W1 + k * 8192;
    float f0 = 0.f, f1 = 0.f, f2 = 0.f, f3 = 0.f;
    float f4 = 0.f, f5 = 0.f, f6 = 0.f, f7 = 0.f;
#pragma unroll 4
    for (int kk = 0; kk < 64; ++kk) {
      float yv = Ys[r * YS_LD + kk];
      float4 w0 = *(const float4*)&W1k[kk * 128 + c8];
      float4 w1 = *(const float4*)&W1k[kk * 128 + c8 + 4];
      f0 = fmaf(yv, w0.x, f0); f1 = fmaf(yv, w0.y, f1);
      f2 = fmaf(yv, w0.z, f2); f3 = fmaf(yv, w0.w, f3);
      f4 = fmaf(yv, w1.x, f4); f5 = fmaf(yv, w1.y, f5);
      f6 = fmaf(yv, w1.z, f6); f7 = fmaf(yv, w1.w, f7);
    }
    {
      float4 ba = *(const float4*)&b1s[c8];
      float4 bb = *(const float4*)&b1s[c8 + 4];
      float4 h0, h1;
      h0.x = fmaxf(f0 + ba.x, 0.f); h0.y = fmaxf(f1 + ba.y, 0.f);
      h0.z = fmaxf(f2 + ba.z, 0.f); h0.w = fmaxf(f3 + ba.w, 0.f);
      h1.x = fmaxf(f4 + bb.x, 0.f); h1.y = fmaxf(f5 + bb.y, 0.f);
      h1.z = fmaxf(f6 + bb.z, 0.f); h1.w = fmaxf(f7 + bb.w, 0.f);
      *(float4*)&Hs[r * HS_LD + c8]     = h0;
      *(float4*)&Hs[r * HS_LD + c8 + 4] = h1;
    }
    __syncthreads();

    // ---- layer 2: out += Hs @ W2 + b2, thread = 1 row x 4 cols ----
    const float* W2k = W2 + k * 8192;
    float o0 = b2s[c4], o1 = b2s[c4 + 1], o2 = b2s[c4 + 2], o3 = b2s[c4 + 3];
#pragma unroll 4
    for (int kk = 0; kk < 128; ++kk) {
      float hv = Hs[r * HS_LD + kk];
      float4 wv = *(const float4*)&W2k[kk * 64 + c4];
      o0 = fmaf(hv, wv.x, o0); o1 = fmaf(hv, wv.y, o1);
      o2 = fmaf(hv, wv.z, o2); o3 = fmaf(hv, wv.w, o3);
    }
    oacc[0] += o0; oacc[1] += o1; oacc[2] += o2; oacc[3] += o3;
    __syncthreads();   // protect Ys/Hs before next branch restage
  }

  float4 v;
  v.x = oacc[0]; v.y = oacc[1]; v.z = oacc[2]; v.w = oacc[3];
  *(float4*)&out[(size_t)(rowBase + r) * 64 + c4] = v;
}

// ---------------------------------------------------------------------------
extern "C" void kernel_launch(void* const* d_in, const int* in_sizes, int n_in,
                              void* d_out, int out_size, void* d_ws, size_t ws_size,
                              hipStream_t stream) {
  const float* x    = (const float*)d_in[0];
  const float* wf   = (const float*)d_in[1];
  const float* hop1 = (const float*)d_in[2];
  const float* hop2 = (const float*)d_in[3];
  const float* hop3 = (const float*)d_in[4];
  const float* W1   = (const float*)d_in[5];
  const float* b1   = (const float*)d_in[6];
  const float* W2   = (const float*)d_in[7];
  const float* b2   = (const float*)d_in[8];
  float* out = (float*)d_out;

  // workspace layout: [0,1MB) packed bf16 X; [1MB, 1MB+6MB) Y[3][8192][64] f32
  unsigned short* Bp = (unsigned short*)d_ws;
  float* Y = (float*)((char*)d_ws + (1 << 20));

  prep_kernel<<<dim3(524288 / 256), dim3(256), 0, stream>>>(x, wf, Bp);
  hop_gemm<<<dim3(1536), dim3(256), 0, stream>>>(hop1, hop2, hop3, Bp, Y);
  mlp_kernel<<<dim3(512), dim3(256), 0, stream>>>(x, wf, Y, W1, b1, W2, b2, out);
}